// Round 1
// baseline (3193.194 us; speedup 1.0000x reference)
//
#include <hip/hip_runtime.h>
#include <math.h>

#define N_NODES 100000
#define N_EDGES 1600000
#define IN_DIM 256
#define OUT_DIM 128
#define NEG_SLOPE 0.2f
#define LAMBDA 0.5f
#define EPS 1e-8f

// ---- workspace layout (float offsets) ----
#define OFF_H     ((size_t)0)          // N*128 = 12.8M floats
#define OFF_XW    ((size_t)12800000)   // N*128
#define OFF_ALPHA ((size_t)25600000)   // E
#define OFF_DENOM ((size_t)27200000)   // N
#define OFF_ASRC  ((size_t)27300000)   // N
#define OFF_ADST  ((size_t)27400000)   // N
#define OFF_SPAIR ((size_t)27500000)   // E int2  (3.2M floats)
#define OFF_CPAIR ((size_t)30700000)   // E float2 (3.2M floats)
#define WS_FLOATS ((size_t)33900000)

// ============================================================
// K1: fused dual GEMM  h = x@Wg^T, xw = x@Wf^T  (+ per-node att scalars)
// tile: 64 nodes x 128 outs, K chunked 128 (x) / 32 (W).
// LDS: xs 64x132 (33.8KB) + wsb 32x132 (16.9KB) = 50.7KB -> 3 blocks/CU
// thread layout: 16x16 (tx=cols/8, ty=nodes/4), micro-tile 4x8 per phase
// ============================================================
__global__ __launch_bounds__(256) void gemm_dual(
    const float* __restrict__ x, const float* __restrict__ Wg,
    const float* __restrict__ Wf,
    const float* __restrict__ att_s, const float* __restrict__ att_d,
    float* __restrict__ h, float* __restrict__ xw,
    float* __restrict__ a_src, float* __restrict__ a_dst)
{
    __shared__ float xs[64 * 132];   // stride 132: 4*132=528 dwords -> bank stride 16 (2-way = free)
    __shared__ float wsb[32 * 132];
    const int tid = threadIdx.x;
    const int tx  = tid & 15;
    const int ty  = tid >> 4;
    const int tx8 = tx * 8;
    const int ty4 = ty * 4;
    const int nb  = blockIdx.x * 64;

    float acc0[4][8], acc1[4][8];
#pragma unroll
    for (int i = 0; i < 4; ++i)
#pragma unroll
        for (int j = 0; j < 8; ++j) { acc0[i][j] = 0.f; acc1[i][j] = 0.f; }

    for (int k0 = 0; k0 < 256; k0 += 128) {
        __syncthreads();
        // stage x tile: 64 rows x 128 k  (2048 float4, 8 per thread, coalesced)
#pragma unroll
        for (int it = 0; it < 8; ++it) {
            int f   = tid + it * 256;
            int row = f >> 5;
            int c4  = (f & 31) << 2;
            int gn  = nb + row; if (gn >= N_NODES) gn = N_NODES - 1;
            float4 v = *(const float4*)(x + (size_t)gn * IN_DIM + k0 + c4);
            *(float4*)(&xs[row * 132 + c4]) = v;
        }
        for (int kc = 0; kc < 128; kc += 32) {
            // ---- phase A: W_gat chunk -> acc0 ----
            __syncthreads();
#pragma unroll
            for (int it = 0; it < 4; ++it) {
                int f   = tid + it * 256;
                int col = f >> 3;
                int kk4 = (f & 7) << 2;
                float4 v = *(const float4*)(Wg + (size_t)col * IN_DIM + k0 + kc + kk4);
                wsb[(kk4 + 0) * 132 + col] = v.x;
                wsb[(kk4 + 1) * 132 + col] = v.y;
                wsb[(kk4 + 2) * 132 + col] = v.z;
                wsb[(kk4 + 3) * 132 + col] = v.w;
            }
            __syncthreads();
#pragma unroll 8
            for (int kk = 0; kk < 32; ++kk) {
                float xv[4];
#pragma unroll
                for (int ni = 0; ni < 4; ++ni) xv[ni] = xs[(ty4 + ni) * 132 + kc + kk];
                float4 w0 = *(const float4*)(&wsb[kk * 132 + tx8]);
                float4 w1 = *(const float4*)(&wsb[kk * 132 + tx8 + 4]);
#pragma unroll
                for (int ni = 0; ni < 4; ++ni) {
                    acc0[ni][0] += xv[ni] * w0.x; acc0[ni][1] += xv[ni] * w0.y;
                    acc0[ni][2] += xv[ni] * w0.z; acc0[ni][3] += xv[ni] * w0.w;
                    acc0[ni][4] += xv[ni] * w1.x; acc0[ni][5] += xv[ni] * w1.y;
                    acc0[ni][6] += xv[ni] * w1.z; acc0[ni][7] += xv[ni] * w1.w;
                }
            }
            // ---- phase B: W_fixed chunk -> acc1 ----
            __syncthreads();
#pragma unroll
            for (int it = 0; it < 4; ++it) {
                int f   = tid + it * 256;
                int col = f >> 3;
                int kk4 = (f & 7) << 2;
                float4 v = *(const float4*)(Wf + (size_t)col * IN_DIM + k0 + kc + kk4);
                wsb[(kk4 + 0) * 132 + col] = v.x;
                wsb[(kk4 + 1) * 132 + col] = v.y;
                wsb[(kk4 + 2) * 132 + col] = v.z;
                wsb[(kk4 + 3) * 132 + col] = v.w;
            }
            __syncthreads();
#pragma unroll 8
            for (int kk = 0; kk < 32; ++kk) {
                float xv[4];
#pragma unroll
                for (int ni = 0; ni < 4; ++ni) xv[ni] = xs[(ty4 + ni) * 132 + kc + kk];
                float4 w0 = *(const float4*)(&wsb[kk * 132 + tx8]);
                float4 w1 = *(const float4*)(&wsb[kk * 132 + tx8 + 4]);
#pragma unroll
                for (int ni = 0; ni < 4; ++ni) {
                    acc1[ni][0] += xv[ni] * w0.x; acc1[ni][1] += xv[ni] * w0.y;
                    acc1[ni][2] += xv[ni] * w0.z; acc1[ni][3] += xv[ni] * w0.w;
                    acc1[ni][4] += xv[ni] * w1.x; acc1[ni][5] += xv[ni] * w1.y;
                    acc1[ni][6] += xv[ni] * w1.z; acc1[ni][7] += xv[ni] * w1.w;
                }
            }
        }
    }

    // ---- stores ----
#pragma unroll
    for (int ni = 0; ni < 4; ++ni) {
        int node = nb + ty4 + ni;
        if (node < N_NODES) {
            float4 o0 = make_float4(acc0[ni][0], acc0[ni][1], acc0[ni][2], acc0[ni][3]);
            float4 o1 = make_float4(acc0[ni][4], acc0[ni][5], acc0[ni][6], acc0[ni][7]);
            *(float4*)(&h[(size_t)node * OUT_DIM + tx8])     = o0;
            *(float4*)(&h[(size_t)node * OUT_DIM + tx8 + 4]) = o1;
            float4 f0 = make_float4(acc1[ni][0], acc1[ni][1], acc1[ni][2], acc1[ni][3]);
            float4 f1 = make_float4(acc1[ni][4], acc1[ni][5], acc1[ni][6], acc1[ni][7]);
            *(float4*)(&xw[(size_t)node * OUT_DIM + tx8])     = f0;
            *(float4*)(&xw[(size_t)node * OUT_DIM + tx8 + 4]) = f1;
        }
    }

    // ---- epilogue: per-node attention scalars (reduce over tx lanes) ----
    float4 s0 = *(const float4*)(att_s + tx8);
    float4 s1 = *(const float4*)(att_s + tx8 + 4);
    float4 d0 = *(const float4*)(att_d + tx8);
    float4 d1 = *(const float4*)(att_d + tx8 + 4);
#pragma unroll
    for (int ni = 0; ni < 4; ++ni) {
        int node = nb + ty4 + ni;
        float ss = acc0[ni][0]*s0.x + acc0[ni][1]*s0.y + acc0[ni][2]*s0.z + acc0[ni][3]*s0.w
                 + acc0[ni][4]*s1.x + acc0[ni][5]*s1.y + acc0[ni][6]*s1.z + acc0[ni][7]*s1.w;
        float dd = acc0[ni][0]*d0.x + acc0[ni][1]*d0.y + acc0[ni][2]*d0.z + acc0[ni][3]*d0.w
                 + acc0[ni][4]*d1.x + acc0[ni][5]*d1.y + acc0[ni][6]*d1.z + acc0[ni][7]*d1.w;
#pragma unroll
        for (int m = 1; m < 16; m <<= 1) {
            ss += __shfl_xor(ss, m);
            dd += __shfl_xor(dd, m);
        }
        if (tx == 0 && node < N_NODES) { a_src[node] = ss; a_dst[node] = dd; }
    }
}

// ============================================================
// K2: per-edge raw attention + denom accumulation (scalar gathers only)
// ============================================================
__global__ __launch_bounds__(256) void edge_alpha(
    const int* __restrict__ ei, const float* __restrict__ a_src,
    const float* __restrict__ a_dst, float* __restrict__ alphaRaw,
    float* __restrict__ denom, int2* __restrict__ spair)
{
    int e = blockIdx.x * 256 + threadIdx.x;
    int s = ei[e];
    int d = ei[N_EDGES + e];
    // clamp: insurance against dtype-width surprises (indices are valid in-range)
    s = s < 0 ? 0 : (s >= N_NODES ? N_NODES - 1 : s);
    d = d < 0 ? 0 : (d >= N_NODES ? N_NODES - 1 : d);
    spair[e] = make_int2(s, d);
    float ev = a_src[s] + a_dst[d];
    ev = ev >= 0.f ? ev : NEG_SLOPE * ev;          // LeakyReLU
    float al = 1.f / (1.f + expf(-ev));            // sigmoid
    alphaRaw[e] = al;
    atomicAdd(denom + d, al);
}

// ============================================================
// K3: per-edge fused coefficients  c1 = lam*alpha/denom, c2 = (1-lam)*beta
// ============================================================
__global__ __launch_bounds__(256) void edge_coef(
    const float* __restrict__ alphaRaw, const float* __restrict__ denom,
    const float* __restrict__ beta, const int2* __restrict__ spair,
    float2* __restrict__ cpair)
{
    int e = blockIdx.x * 256 + threadIdx.x;
    int d = spair[e].y;
    float c1 = LAMBDA * alphaRaw[e] / (denom[d] + EPS);
    float c2 = (1.f - LAMBDA) * beta[e];
    cpair[e] = make_float2(c1, c2);
}

// ============================================================
// K4: fused scatter  acc[dst] += c1*h[src] + c2*xw[src]
// 32 threads per edge, float4 per thread, 4 float atomics per thread
// ============================================================
__global__ __launch_bounds__(256) void edge_scatter(
    const float* __restrict__ h, const float* __restrict__ xw,
    const int2* __restrict__ spair, const float2* __restrict__ cpair,
    float* __restrict__ acc)
{
    long long g = (long long)blockIdx.x * 256 + threadIdx.x;
    int e = (int)(g >> 5);
    int j = ((int)g & 31) << 2;
    int2   sd = spair[e];
    float2 c  = cpair[e];
    float4 hv = *(const float4*)(h  + (size_t)sd.x * OUT_DIM + j);
    float4 wv = *(const float4*)(xw + (size_t)sd.x * OUT_DIM + j);
    float* dp = acc + (size_t)sd.y * OUT_DIM + j;
    atomicAdd(dp + 0, c.x * hv.x + c.y * wv.x);
    atomicAdd(dp + 1, c.x * hv.y + c.y * wv.y);
    atomicAdd(dp + 2, c.x * hv.z + c.y * wv.z);
    atomicAdd(dp + 3, c.x * hv.w + c.y * wv.w);
}

// ============================================================
// K5: finalize  out = elu(acc + lam*bias)
// ============================================================
__global__ __launch_bounds__(256) void finalize_kernel(
    float* __restrict__ out, const float* __restrict__ bias)
{
    int i4 = blockIdx.x * 256 + threadIdx.x;     // float4 index
    float4 v = *(float4*)(out + (size_t)i4 * 4);
    int col = (i4 & 31) * 4;
    float4 b = *(const float4*)(bias + col);
    v.x += LAMBDA * b.x; v.y += LAMBDA * b.y; v.z += LAMBDA * b.z; v.w += LAMBDA * b.w;
    v.x = v.x > 0.f ? v.x : expm1f(v.x);
    v.y = v.y > 0.f ? v.y : expm1f(v.y);
    v.z = v.z > 0.f ? v.z : expm1f(v.z);
    v.w = v.w > 0.f ? v.w : expm1f(v.w);
    *(float4*)(out + (size_t)i4 * 4) = v;
}

extern "C" void kernel_launch(void* const* d_in, const int* in_sizes, int n_in,
                              void* d_out, int out_size, void* d_ws, size_t ws_size,
                              hipStream_t stream)
{
    const float* x     = (const float*)d_in[0];
    const int*   ei    = (const int*)d_in[1];
    const float* beta  = (const float*)d_in[2];
    const float* Wg    = (const float*)d_in[3];
    const float* att_s = (const float*)d_in[4];
    const float* att_d = (const float*)d_in[5];
    const float* bias  = (const float*)d_in[6];
    const float* Wf    = (const float*)d_in[7];
    float* out = (float*)d_out;
    float* ws  = (float*)d_ws;

    if (ws_size < WS_FLOATS * sizeof(float)) return;  // visible failure if scratch too small

    float*  h     = ws + OFF_H;
    float*  xw    = ws + OFF_XW;
    float*  alph  = ws + OFF_ALPHA;
    float*  denom = ws + OFF_DENOM;
    float*  asrc  = ws + OFF_ASRC;
    float*  adst  = ws + OFF_ADST;
    int2*   spair = (int2*)(ws + OFF_SPAIR);
    float2* cpair = (float2*)(ws + OFF_CPAIR);

    hipMemsetAsync(out, 0, (size_t)N_NODES * OUT_DIM * sizeof(float), stream);
    hipMemsetAsync(denom, 0, (size_t)N_NODES * sizeof(float), stream);

    gemm_dual<<<(N_NODES + 63) / 64, 256, 0, stream>>>(x, Wg, Wf, att_s, att_d, h, xw, asrc, adst);
    edge_alpha<<<N_EDGES / 256, 256, 0, stream>>>(ei, asrc, adst, alph, denom, spair);
    edge_coef<<<N_EDGES / 256, 256, 0, stream>>>(alph, denom, beta, spair, cpair);
    edge_scatter<<<(N_EDGES / 256) * 32, 256, 0, stream>>>(h, xw, spair, cpair, out);
    finalize_kernel<<<N_NODES * OUT_DIM / 4 / 256, 256, 0, stream>>>(out, bias);
}

// Round 2
// 814.933 us; speedup vs baseline: 3.9184x; 3.9184x over previous
//
#include <hip/hip_runtime.h>
#include <math.h>

#define N_NODES 100000
#define N_EDGES 1600000
#define IN_DIM 256
#define OUT_DIM 128
#define NEG_SLOPE 0.2f
#define LAMBDA 0.5f
#define EPS 1e-8f

// ---- workspace layout (float offsets) ----
#define OFF_HX    ((size_t)0)          // N*256 interleaved [h row | xw row]
#define OFF_ASRC  ((size_t)25600000)   // N
#define OFF_ADST  ((size_t)25700000)   // N
#define OFF_DENOM ((size_t)25800000)   // N
#define OFF_COUNT ((size_t)25900000)   // N (int)
#define OFF_OFFS  ((size_t)26000000)   // N (int)  exclusive scan of count
#define OFF_CURS  ((size_t)26100000)   // N (int)  consumable cursor copy
#define OFF_BSUM  ((size_t)26200000)   // 1024 (int) block sums
#define OFF_REC   ((size_t)26201024)   // E float4 sorted records (div by 4 -> 16B aligned)
#define WS_FLOATS ((size_t)32601024)   // ~130.4 MB (proven available in R1)

#define SCAN_BLOCKS ((N_NODES + 255) / 256)   // 391

// ============================================================
// K1: fused dual GEMM  hx[n][0:128]=x@Wg^T, hx[n][128:256]=x@Wf^T
//     + per-node attention scalars a_src=h.att_s, a_dst=h.att_d
// ============================================================
__global__ __launch_bounds__(256) void gemm_dual(
    const float* __restrict__ x, const float* __restrict__ Wg,
    const float* __restrict__ Wf,
    const float* __restrict__ att_s, const float* __restrict__ att_d,
    float* __restrict__ hx,
    float* __restrict__ a_src, float* __restrict__ a_dst)
{
    __shared__ float xs[64 * 132];
    __shared__ float wsb[32 * 132];
    const int tid = threadIdx.x;
    const int tx  = tid & 15;
    const int ty  = tid >> 4;
    const int tx8 = tx * 8;
    const int ty4 = ty * 4;
    const int nb  = blockIdx.x * 64;

    float acc0[4][8], acc1[4][8];
#pragma unroll
    for (int i = 0; i < 4; ++i)
#pragma unroll
        for (int j = 0; j < 8; ++j) { acc0[i][j] = 0.f; acc1[i][j] = 0.f; }

    for (int k0 = 0; k0 < 256; k0 += 128) {
        __syncthreads();
#pragma unroll
        for (int it = 0; it < 8; ++it) {
            int f   = tid + it * 256;
            int row = f >> 5;
            int c4  = (f & 31) << 2;
            int gn  = nb + row; if (gn >= N_NODES) gn = N_NODES - 1;
            float4 v = *(const float4*)(x + (size_t)gn * IN_DIM + k0 + c4);
            *(float4*)(&xs[row * 132 + c4]) = v;
        }
        for (int kc = 0; kc < 128; kc += 32) {
            __syncthreads();
#pragma unroll
            for (int it = 0; it < 4; ++it) {
                int f   = tid + it * 256;
                int col = f >> 3;
                int kk4 = (f & 7) << 2;
                float4 v = *(const float4*)(Wg + (size_t)col * IN_DIM + k0 + kc + kk4);
                wsb[(kk4 + 0) * 132 + col] = v.x;
                wsb[(kk4 + 1) * 132 + col] = v.y;
                wsb[(kk4 + 2) * 132 + col] = v.z;
                wsb[(kk4 + 3) * 132 + col] = v.w;
            }
            __syncthreads();
#pragma unroll 8
            for (int kk = 0; kk < 32; ++kk) {
                float xv[4];
#pragma unroll
                for (int ni = 0; ni < 4; ++ni) xv[ni] = xs[(ty4 + ni) * 132 + kc + kk];
                float4 w0 = *(const float4*)(&wsb[kk * 132 + tx8]);
                float4 w1 = *(const float4*)(&wsb[kk * 132 + tx8 + 4]);
#pragma unroll
                for (int ni = 0; ni < 4; ++ni) {
                    acc0[ni][0] += xv[ni] * w0.x; acc0[ni][1] += xv[ni] * w0.y;
                    acc0[ni][2] += xv[ni] * w0.z; acc0[ni][3] += xv[ni] * w0.w;
                    acc0[ni][4] += xv[ni] * w1.x; acc0[ni][5] += xv[ni] * w1.y;
                    acc0[ni][6] += xv[ni] * w1.z; acc0[ni][7] += xv[ni] * w1.w;
                }
            }
            __syncthreads();
#pragma unroll
            for (int it = 0; it < 4; ++it) {
                int f   = tid + it * 256;
                int col = f >> 3;
                int kk4 = (f & 7) << 2;
                float4 v = *(const float4*)(Wf + (size_t)col * IN_DIM + k0 + kc + kk4);
                wsb[(kk4 + 0) * 132 + col] = v.x;
                wsb[(kk4 + 1) * 132 + col] = v.y;
                wsb[(kk4 + 2) * 132 + col] = v.z;
                wsb[(kk4 + 3) * 132 + col] = v.w;
            }
            __syncthreads();
#pragma unroll 8
            for (int kk = 0; kk < 32; ++kk) {
                float xv[4];
#pragma unroll
                for (int ni = 0; ni < 4; ++ni) xv[ni] = xs[(ty4 + ni) * 132 + kc + kk];
                float4 w0 = *(const float4*)(&wsb[kk * 132 + tx8]);
                float4 w1 = *(const float4*)(&wsb[kk * 132 + tx8 + 4]);
#pragma unroll
                for (int ni = 0; ni < 4; ++ni) {
                    acc1[ni][0] += xv[ni] * w0.x; acc1[ni][1] += xv[ni] * w0.y;
                    acc1[ni][2] += xv[ni] * w0.z; acc1[ni][3] += xv[ni] * w0.w;
                    acc1[ni][4] += xv[ni] * w1.x; acc1[ni][5] += xv[ni] * w1.y;
                    acc1[ni][6] += xv[ni] * w1.z; acc1[ni][7] += xv[ni] * w1.w;
                }
            }
        }
    }

#pragma unroll
    for (int ni = 0; ni < 4; ++ni) {
        int node = nb + ty4 + ni;
        if (node < N_NODES) {
            size_t base = (size_t)node * 256;
            *(float4*)(&hx[base + tx8])           = make_float4(acc0[ni][0], acc0[ni][1], acc0[ni][2], acc0[ni][3]);
            *(float4*)(&hx[base + tx8 + 4])       = make_float4(acc0[ni][4], acc0[ni][5], acc0[ni][6], acc0[ni][7]);
            *(float4*)(&hx[base + 128 + tx8])     = make_float4(acc1[ni][0], acc1[ni][1], acc1[ni][2], acc1[ni][3]);
            *(float4*)(&hx[base + 128 + tx8 + 4]) = make_float4(acc1[ni][4], acc1[ni][5], acc1[ni][6], acc1[ni][7]);
        }
    }

    float4 s0 = *(const float4*)(att_s + tx8);
    float4 s1 = *(const float4*)(att_s + tx8 + 4);
    float4 d0 = *(const float4*)(att_d + tx8);
    float4 d1 = *(const float4*)(att_d + tx8 + 4);
#pragma unroll
    for (int ni = 0; ni < 4; ++ni) {
        int node = nb + ty4 + ni;
        float ss = acc0[ni][0]*s0.x + acc0[ni][1]*s0.y + acc0[ni][2]*s0.z + acc0[ni][3]*s0.w
                 + acc0[ni][4]*s1.x + acc0[ni][5]*s1.y + acc0[ni][6]*s1.z + acc0[ni][7]*s1.w;
        float dd = acc0[ni][0]*d0.x + acc0[ni][1]*d0.y + acc0[ni][2]*d0.z + acc0[ni][3]*d0.w
                 + acc0[ni][4]*d1.x + acc0[ni][5]*d1.y + acc0[ni][6]*d1.z + acc0[ni][7]*d1.w;
#pragma unroll
        for (int m = 1; m < 16; m <<= 1) {
            ss += __shfl_xor(ss, m);
            dd += __shfl_xor(dd, m);
        }
        if (tx == 0 && node < N_NODES) { a_src[node] = ss; a_dst[node] = dd; }
    }
}

// ============================================================
// K2: per-edge alpha -> denom atomic + per-dst count
// ============================================================
__global__ __launch_bounds__(256) void edge_alpha(
    const int* __restrict__ ei, const float* __restrict__ a_src,
    const float* __restrict__ a_dst, float* __restrict__ denom,
    int* __restrict__ count)
{
    int e = blockIdx.x * 256 + threadIdx.x;
    int s = ei[e];
    int d = ei[N_EDGES + e];
    s = s < 0 ? 0 : (s >= N_NODES ? N_NODES - 1 : s);
    d = d < 0 ? 0 : (d >= N_NODES ? N_NODES - 1 : d);
    float ev = a_src[s] + a_dst[d];
    ev = ev >= 0.f ? ev : NEG_SLOPE * ev;
    float al = 1.f / (1.f + expf(-ev));
    atomicAdd(denom + d, al);
    atomicAdd(count + d, 1);
}

// ============================================================
// K3a/b/c: exclusive scan of count (100K) -> offs, cursor
// ============================================================
__global__ __launch_bounds__(256) void scan1(
    const int* __restrict__ count, int* __restrict__ offs, int* __restrict__ bsum)
{
    __shared__ int s[256];
    int i = blockIdx.x * 256 + threadIdx.x;
    int v = (i < N_NODES) ? count[i] : 0;
    s[threadIdx.x] = v;
    __syncthreads();
    for (int off = 1; off < 256; off <<= 1) {
        int t = (threadIdx.x >= off) ? s[threadIdx.x - off] : 0;
        __syncthreads();
        s[threadIdx.x] += t;
        __syncthreads();
    }
    if (i < N_NODES) offs[i] = s[threadIdx.x] - v;   // exclusive within block
    if (threadIdx.x == 255) bsum[blockIdx.x] = s[255];
}

__global__ __launch_bounds__(512) void scan2(int* __restrict__ bsum)
{
    __shared__ int s[512];
    int v = (threadIdx.x < SCAN_BLOCKS) ? bsum[threadIdx.x] : 0;
    s[threadIdx.x] = v;
    __syncthreads();
    for (int off = 1; off < 512; off <<= 1) {
        int t = (threadIdx.x >= off) ? s[threadIdx.x - off] : 0;
        __syncthreads();
        s[threadIdx.x] += t;
        __syncthreads();
    }
    if (threadIdx.x < SCAN_BLOCKS) bsum[threadIdx.x] = s[threadIdx.x] - v; // exclusive
}

__global__ __launch_bounds__(256) void scan3(
    int* __restrict__ offs, const int* __restrict__ bsum, int* __restrict__ cursor)
{
    int i = blockIdx.x * 256 + threadIdx.x;
    if (i < N_NODES) {
        int v = offs[i] + bsum[blockIdx.x];
        offs[i]   = v;
        cursor[i] = v;
    }
}

// ============================================================
// K4: scatter sorted records  rec[pos] = (src, c1, c2, _)
// ============================================================
__global__ __launch_bounds__(256) void scatter_rec(
    const int* __restrict__ ei, const float* __restrict__ a_src,
    const float* __restrict__ a_dst, const float* __restrict__ denom,
    const float* __restrict__ beta, int* __restrict__ cursor,
    float4* __restrict__ rec)
{
    int e = blockIdx.x * 256 + threadIdx.x;
    int s = ei[e];
    int d = ei[N_EDGES + e];
    s = s < 0 ? 0 : (s >= N_NODES ? N_NODES - 1 : s);
    d = d < 0 ? 0 : (d >= N_NODES ? N_NODES - 1 : d);
    float ev = a_src[s] + a_dst[d];
    ev = ev >= 0.f ? ev : NEG_SLOPE * ev;
    float al = 1.f / (1.f + expf(-ev));
    float c1 = LAMBDA * al / (denom[d] + EPS);
    float c2 = (1.f - LAMBDA) * beta[e];
    int pos = atomicAdd(cursor + d, 1);
    rec[pos] = make_float4(__int_as_float(s), c1, c2, 0.f);
}

// ============================================================
// K5: segmented reduce — one wave per dst node, no atomics.
// lanes 0-31: h half (coef c1); lanes 32-63: xw half (coef c2).
// Per edge: 16B broadcast rec load + 1KB coalesced hx row load.
// ============================================================
__global__ __launch_bounds__(256) void segment_reduce(
    const float* __restrict__ hx, const float4* __restrict__ rec,
    const int* __restrict__ offs, const int* __restrict__ count,
    const float* __restrict__ bias, float* __restrict__ out)
{
    int wave = (blockIdx.x * 256 + threadIdx.x) >> 6;
    int lane = threadIdx.x & 63;
    if (wave >= N_NODES) return;
    int start = offs[wave];
    int cnt   = count[wave];
    const bool hhalf = lane < 32;
    const int  l4    = lane * 4;

    float4 acc = make_float4(0.f, 0.f, 0.f, 0.f);
    int k = 0;
    for (; k + 2 <= cnt; k += 2) {
        float4 r0 = rec[start + k];
        float4 r1 = rec[start + k + 1];
        int s0 = __float_as_int(r0.x);
        int s1 = __float_as_int(r1.x);
        float c0 = hhalf ? r0.y : r0.z;
        float c1 = hhalf ? r1.y : r1.z;
        float4 v0 = *(const float4*)(hx + (size_t)s0 * 256 + l4);
        float4 v1 = *(const float4*)(hx + (size_t)s1 * 256 + l4);
        acc.x += c0 * v0.x; acc.y += c0 * v0.y; acc.z += c0 * v0.z; acc.w += c0 * v0.w;
        acc.x += c1 * v1.x; acc.y += c1 * v1.y; acc.z += c1 * v1.z; acc.w += c1 * v1.w;
    }
    if (k < cnt) {
        float4 r0 = rec[start + k];
        int s0 = __float_as_int(r0.x);
        float c0 = hhalf ? r0.y : r0.z;
        float4 v0 = *(const float4*)(hx + (size_t)s0 * 256 + l4);
        acc.x += c0 * v0.x; acc.y += c0 * v0.y; acc.z += c0 * v0.z; acc.w += c0 * v0.w;
    }

    // combine h-half (lanes 0-31) with xw-half (lanes 32-63)
    acc.x += __shfl_xor(acc.x, 32);
    acc.y += __shfl_xor(acc.y, 32);
    acc.z += __shfl_xor(acc.z, 32);
    acc.w += __shfl_xor(acc.w, 32);

    if (hhalf) {
        float4 b = *(const float4*)(bias + l4);
        float4 o;
        o.x = acc.x + LAMBDA * b.x;
        o.y = acc.y + LAMBDA * b.y;
        o.z = acc.z + LAMBDA * b.z;
        o.w = acc.w + LAMBDA * b.w;
        o.x = o.x > 0.f ? o.x : expm1f(o.x);
        o.y = o.y > 0.f ? o.y : expm1f(o.y);
        o.z = o.z > 0.f ? o.z : expm1f(o.z);
        o.w = o.w > 0.f ? o.w : expm1f(o.w);
        *(float4*)(out + (size_t)wave * OUT_DIM + l4) = o;
    }
}

extern "C" void kernel_launch(void* const* d_in, const int* in_sizes, int n_in,
                              void* d_out, int out_size, void* d_ws, size_t ws_size,
                              hipStream_t stream)
{
    const float* x     = (const float*)d_in[0];
    const int*   ei    = (const int*)d_in[1];
    const float* beta  = (const float*)d_in[2];
    const float* Wg    = (const float*)d_in[3];
    const float* att_s = (const float*)d_in[4];
    const float* att_d = (const float*)d_in[5];
    const float* bias  = (const float*)d_in[6];
    const float* Wf    = (const float*)d_in[7];
    float* out = (float*)d_out;
    float* ws  = (float*)d_ws;

    if (ws_size < WS_FLOATS * sizeof(float)) return;

    float*  hx     = ws + OFF_HX;
    float*  asrc   = ws + OFF_ASRC;
    float*  adst   = ws + OFF_ADST;
    float*  denom  = ws + OFF_DENOM;
    int*    count  = (int*)(ws + OFF_COUNT);
    int*    offs   = (int*)(ws + OFF_OFFS);
    int*    cursor = (int*)(ws + OFF_CURS);
    int*    bsum   = (int*)(ws + OFF_BSUM);
    float4* rec    = (float4*)(ws + OFF_REC);

    hipMemsetAsync(denom, 0, (size_t)N_NODES * sizeof(float), stream);
    hipMemsetAsync(count, 0, (size_t)N_NODES * sizeof(int), stream);

    gemm_dual<<<(N_NODES + 63) / 64, 256, 0, stream>>>(x, Wg, Wf, att_s, att_d, hx, asrc, adst);
    edge_alpha<<<N_EDGES / 256, 256, 0, stream>>>(ei, asrc, adst, denom, count);
    scan1<<<SCAN_BLOCKS, 256, 0, stream>>>(count, offs, bsum);
    scan2<<<1, 512, 0, stream>>>(bsum);
    scan3<<<SCAN_BLOCKS, 256, 0, stream>>>(offs, bsum, cursor);
    scatter_rec<<<N_EDGES / 256, 256, 0, stream>>>(ei, asrc, adst, denom, beta, cursor, rec);
    segment_reduce<<<(N_NODES * 64 + 255) / 256, 256, 0, stream>>>(hx, rec, offs, count, bias, out);
}

// Round 3
// 592.758 us; speedup vs baseline: 5.3870x; 1.3748x over previous
//
#include <hip/hip_runtime.h>
#include <math.h>

#define N_NODES 100000
#define N_EDGES 1600000
#define IN_DIM 256
#define OUT_DIM 128
#define NEG_SLOPE 0.2f
#define LAMBDA 0.5f
#define EPS 1e-8f

// ---- workspace layout (float offsets) ----
#define OFF_HB    ((size_t)0)          // N*128 bf16 (ushort)  h
#define OFF_XB    ((size_t)6400000)    // N*128 bf16 (ushort)  xW_fixed
#define OFF_WC    ((size_t)12800000)   // 256x256 bf16  [Wg ; Wf] rows
#define OFF_ASRC  ((size_t)12832768)   // N float
#define OFF_ADST  ((size_t)12932768)   // N float
#define OFF_DENOM ((size_t)13032768)   // N float
#define OFF_COUNT ((size_t)13132768)   // N int
#define OFF_OFFS  ((size_t)13232768)   // N int
#define OFF_CURS  ((size_t)13332768)   // N int
#define OFF_BSUM  ((size_t)13432768)   // 1024 int
#define OFF_REC   ((size_t)13433792)   // E float4 (16B aligned: /4 ok)
#define WS_FLOATS ((size_t)19833792)   // ~79.3 MB

#define SCAN_BLOCKS ((N_NODES + 255) / 256)   // 391

typedef __attribute__((ext_vector_type(8))) short bf16x8;
typedef __attribute__((ext_vector_type(4))) float f32x4;

__device__ __forceinline__ unsigned short f2b(float f) {
    unsigned u = __float_as_uint(f);
    u += 0x7FFFu + ((u >> 16) & 1u);   // RNE (inputs finite)
    return (unsigned short)(u >> 16);
}
__device__ __forceinline__ float b2f_lo(unsigned u) { return __uint_as_float(u << 16); }
__device__ __forceinline__ float b2f_hi(unsigned u) { return __uint_as_float(u & 0xFFFF0000u); }

// ============================================================
// K0: pack [Wg ; Wf] (each 128x256 fp32, row-major) -> Wc bf16 256x256
// ============================================================
__global__ __launch_bounds__(256) void convert_w(
    const float* __restrict__ Wg, const float* __restrict__ Wf,
    ushort* __restrict__ Wc)
{
    int g = blockIdx.x * 256 + threadIdx.x;   // float4 index, 16384 total
    int e4  = g * 4;
    int row = e4 >> 8;
    int col = e4 & 255;
    const float* src = (row < 128) ? (Wg + (size_t)row * 256 + col)
                                   : (Wf + (size_t)(row - 128) * 256 + col);
    float4 v = *(const float4*)src;
    ushort4 p;
    p.x = f2b(v.x); p.y = f2b(v.y); p.z = f2b(v.z); p.w = f2b(v.w);
    *(ushort4*)(Wc + (size_t)row * 256 + col) = p;
}

// ============================================================
// K1: bf16 MFMA GEMM  [h | xw] = x @ Wc^T   (64 nodes x 256 cols / block)
// A: LDS row-major stride 264 (16B-aligned rows, uniform banks)
// B: LDS block-major [kb 0..3][n 0..255][j 0..7] (16B granules, no pad needed)
// wave w covers cols w*64..w*64+63; waves 0,1 -> h, waves 2,3 -> xw
// ============================================================
__global__ __launch_bounds__(256) void gemm_mfma(
    const float* __restrict__ x, const ushort* __restrict__ Wc,
    ushort* __restrict__ hb, ushort* __restrict__ xb)
{
    __shared__ ushort As[64 * 264];      // 33.8 KB
    __shared__ ushort Bs[4 * 256 * 8];   // 16 KB  -> total 49 KB: 3 blocks/CU
    const int tid  = threadIdx.x;
    const int wv   = tid >> 6;
    const int lane = tid & 63;
    const int quad = lane >> 4;
    const int l16  = lane & 15;
    const int nb   = blockIdx.x * 64;

    f32x4 acc[4][4];
#pragma unroll
    for (int mt = 0; mt < 4; ++mt)
#pragma unroll
        for (int nt = 0; nt < 4; ++nt) acc[mt][nt] = (f32x4){0.f, 0.f, 0.f, 0.f};

    // ---- stage A tile: 64 rows x 256 k, fp32 -> bf16 ----
#pragma unroll
    for (int it = 0; it < 16; ++it) {
        int f   = tid + it * 256;
        int row = f >> 6;
        int c4  = (f & 63) << 2;
        int gn  = nb + row; if (gn >= N_NODES) gn = N_NODES - 1;
        float4 v = *(const float4*)(x + (size_t)gn * IN_DIM + c4);
        ushort4 p;
        p.x = f2b(v.x); p.y = f2b(v.y); p.z = f2b(v.z); p.w = f2b(v.w);
        *(ushort4*)(&As[row * 264 + c4]) = p;
    }

    for (int kc = 0; kc < 256; kc += 32) {
        __syncthreads();                       // Bs reuse fence (covers As on iter 0)
        // ---- stage B chunk: Wc[n][kc..kc+31] -> Bs[kb][n][.] ----
        {
            const int n = tid;
#pragma unroll
            for (int b = 0; b < 4; ++b) {
                bf16x8 w = *(const bf16x8*)(Wc + (size_t)n * 256 + kc + b * 8);
                *(bf16x8*)(&Bs[((size_t)b * 256 + n) * 8]) = w;
            }
        }
        __syncthreads();

        bf16x8 afr[4], bfr[4];
#pragma unroll
        for (int mt = 0; mt < 4; ++mt)
            afr[mt] = *(const bf16x8*)(&As[(mt * 16 + l16) * 264 + kc + quad * 8]);
#pragma unroll
        for (int nt = 0; nt < 4; ++nt) {
            int n = wv * 64 + nt * 16 + l16;
            bfr[nt] = *(const bf16x8*)(&Bs[((size_t)quad * 256 + n) * 8]);
        }
#pragma unroll
        for (int mt = 0; mt < 4; ++mt)
#pragma unroll
            for (int nt = 0; nt < 4; ++nt)
                acc[mt][nt] = __builtin_amdgcn_mfma_f32_16x16x32_bf16(
                    afr[mt], bfr[nt], acc[mt][nt], 0, 0, 0);
    }

    // ---- epilogue: D[row][col] row=quad*4+r, col=l16 (m91-verified layout) ----
    ushort* outp = (wv < 2) ? hb : xb;
    const int ncol0 = (wv & 1) * 64;
#pragma unroll
    for (int mt = 0; mt < 4; ++mt) {
#pragma unroll
        for (int nt = 0; nt < 4; ++nt) {
            int coln = ncol0 + nt * 16 + l16;
#pragma unroll
            for (int r = 0; r < 4; ++r) {
                int node = nb + mt * 16 + quad * 4 + r;
                if (node < N_NODES)
                    outp[(size_t)node * 128 + coln] = f2b(acc[mt][nt][r]);
            }
        }
    }
}

// ============================================================
// K2: per-node attention scalars  a_src = h . att_s, a_dst = h . att_d
// 32 lanes per node, uint2 (4 bf16) per lane
// ============================================================
__global__ __launch_bounds__(256) void node_scalars(
    const ushort* __restrict__ hb, const float* __restrict__ att_s,
    const float* __restrict__ att_d, float* __restrict__ a_src,
    float* __restrict__ a_dst)
{
    int node = blockIdx.x * 8 + (threadIdx.x >> 5);
    int l    = threadIdx.x & 31;
    if (node >= N_NODES) return;
    uint2 u = *(const uint2*)(hb + (size_t)node * 128 + l * 4);
    float f0 = b2f_lo(u.x), f1 = b2f_hi(u.x), f2 = b2f_lo(u.y), f3 = b2f_hi(u.y);
    float4 s = *(const float4*)(att_s + l * 4);
    float4 d = *(const float4*)(att_d + l * 4);
    float ss = f0 * s.x + f1 * s.y + f2 * s.z + f3 * s.w;
    float dd = f0 * d.x + f1 * d.y + f2 * d.z + f3 * d.w;
#pragma unroll
    for (int m = 1; m < 32; m <<= 1) {
        ss += __shfl_xor(ss, m);
        dd += __shfl_xor(dd, m);
    }
    if (l == 0) { a_src[node] = ss; a_dst[node] = dd; }
}

// ============================================================
// K3: per-edge alpha -> denom atomic + per-dst count
// ============================================================
__global__ __launch_bounds__(256) void edge_alpha(
    const int* __restrict__ ei, const float* __restrict__ a_src,
    const float* __restrict__ a_dst, float* __restrict__ denom,
    int* __restrict__ count)
{
    int e = blockIdx.x * 256 + threadIdx.x;
    int s = ei[e];
    int d = ei[N_EDGES + e];
    s = s < 0 ? 0 : (s >= N_NODES ? N_NODES - 1 : s);
    d = d < 0 ? 0 : (d >= N_NODES ? N_NODES - 1 : d);
    float ev = a_src[s] + a_dst[d];
    ev = ev >= 0.f ? ev : NEG_SLOPE * ev;
    float al = 1.f / (1.f + expf(-ev));
    atomicAdd(denom + d, al);
    atomicAdd(count + d, 1);
}

// ============================================================
// K4a/b/c: exclusive scan of count -> offs, cursor
// ============================================================
__global__ __launch_bounds__(256) void scan1(
    const int* __restrict__ count, int* __restrict__ offs, int* __restrict__ bsum)
{
    __shared__ int s[256];
    int i = blockIdx.x * 256 + threadIdx.x;
    int v = (i < N_NODES) ? count[i] : 0;
    s[threadIdx.x] = v;
    __syncthreads();
    for (int off = 1; off < 256; off <<= 1) {
        int t = (threadIdx.x >= off) ? s[threadIdx.x - off] : 0;
        __syncthreads();
        s[threadIdx.x] += t;
        __syncthreads();
    }
    if (i < N_NODES) offs[i] = s[threadIdx.x] - v;
    if (threadIdx.x == 255) bsum[blockIdx.x] = s[255];
}

__global__ __launch_bounds__(512) void scan2(int* __restrict__ bsum)
{
    __shared__ int s[512];
    int v = (threadIdx.x < SCAN_BLOCKS) ? bsum[threadIdx.x] : 0;
    s[threadIdx.x] = v;
    __syncthreads();
    for (int off = 1; off < 512; off <<= 1) {
        int t = (threadIdx.x >= off) ? s[threadIdx.x - off] : 0;
        __syncthreads();
        s[threadIdx.x] += t;
        __syncthreads();
    }
    if (threadIdx.x < SCAN_BLOCKS) bsum[threadIdx.x] = s[threadIdx.x] - v;
}

__global__ __launch_bounds__(256) void scan3(
    int* __restrict__ offs, const int* __restrict__ bsum, int* __restrict__ cursor)
{
    int i = blockIdx.x * 256 + threadIdx.x;
    if (i < N_NODES) {
        int v = offs[i] + bsum[blockIdx.x];
        offs[i]   = v;
        cursor[i] = v;
    }
}

// ============================================================
// K5: scatter sorted records  rec[pos] = (src, c1, c2, _)
// ============================================================
__global__ __launch_bounds__(256) void scatter_rec(
    const int* __restrict__ ei, const float* __restrict__ a_src,
    const float* __restrict__ a_dst, const float* __restrict__ denom,
    const float* __restrict__ beta, int* __restrict__ cursor,
    float4* __restrict__ rec)
{
    int e = blockIdx.x * 256 + threadIdx.x;
    int s = ei[e];
    int d = ei[N_EDGES + e];
    s = s < 0 ? 0 : (s >= N_NODES ? N_NODES - 1 : s);
    d = d < 0 ? 0 : (d >= N_NODES ? N_NODES - 1 : d);
    float ev = a_src[s] + a_dst[d];
    ev = ev >= 0.f ? ev : NEG_SLOPE * ev;
    float al = 1.f / (1.f + expf(-ev));
    float c1 = LAMBDA * al / (denom[d] + EPS);
    float c2 = (1.f - LAMBDA) * beta[e];
    int pos = atomicAdd(cursor + d, 1);
    rec[pos] = make_float4(__int_as_float(s), c1, c2, 0.f);
}

// ============================================================
// K6: segmented reduce — one wave per dst node, bf16 gathers, no atomics.
// lanes 0-31: h half (c1); lanes 32-63: xw half (c2). 8B/lane per edge.
// ============================================================
__global__ __launch_bounds__(256) void segment_reduce(
    const ushort* __restrict__ hb, const ushort* __restrict__ xb,
    const float4* __restrict__ rec, const int* __restrict__ offs,
    const int* __restrict__ count, const float* __restrict__ bias,
    float* __restrict__ out)
{
    int wave = (blockIdx.x * 256 + threadIdx.x) >> 6;
    int lane = threadIdx.x & 63;
    if (wave >= N_NODES) return;
    int start = offs[wave];
    int cnt   = count[wave];
    const bool hhalf = lane < 32;
    const ushort* base = hhalf ? hb : xb;
    const int l4 = (lane & 31) * 4;

    float4 acc = make_float4(0.f, 0.f, 0.f, 0.f);
    int k = 0;
    for (; k + 2 <= cnt; k += 2) {
        float4 r0 = rec[start + k];
        float4 r1 = rec[start + k + 1];
        int   s0 = __float_as_int(r0.x);
        int   s1 = __float_as_int(r1.x);
        float c0 = hhalf ? r0.y : r0.z;
        float c1 = hhalf ? r1.y : r1.z;
        uint2 u0 = *(const uint2*)(base + (size_t)s0 * 128 + l4);
        uint2 u1 = *(const uint2*)(base + (size_t)s1 * 128 + l4);
        acc.x += c0 * b2f_lo(u0.x); acc.y += c0 * b2f_hi(u0.x);
        acc.z += c0 * b2f_lo(u0.y); acc.w += c0 * b2f_hi(u0.y);
        acc.x += c1 * b2f_lo(u1.x); acc.y += c1 * b2f_hi(u1.x);
        acc.z += c1 * b2f_lo(u1.y); acc.w += c1 * b2f_hi(u1.y);
    }
    if (k < cnt) {
        float4 r0 = rec[start + k];
        int   s0 = __float_as_int(r0.x);
        float c0 = hhalf ? r0.y : r0.z;
        uint2 u0 = *(const uint2*)(base + (size_t)s0 * 128 + l4);
        acc.x += c0 * b2f_lo(u0.x); acc.y += c0 * b2f_hi(u0.x);
        acc.z += c0 * b2f_lo(u0.y); acc.w += c0 * b2f_hi(u0.y);
    }

    acc.x += __shfl_xor(acc.x, 32);
    acc.y += __shfl_xor(acc.y, 32);
    acc.z += __shfl_xor(acc.z, 32);
    acc.w += __shfl_xor(acc.w, 32);

    if (hhalf) {
        float4 b = *(const float4*)(bias + l4);
        float4 o;
        o.x = acc.x + LAMBDA * b.x;
        o.y = acc.y + LAMBDA * b.y;
        o.z = acc.z + LAMBDA * b.z;
        o.w = acc.w + LAMBDA * b.w;
        o.x = o.x > 0.f ? o.x : expm1f(o.x);
        o.y = o.y > 0.f ? o.y : expm1f(o.y);
        o.z = o.z > 0.f ? o.z : expm1f(o.z);
        o.w = o.w > 0.f ? o.w : expm1f(o.w);
        *(float4*)(out + (size_t)wave * OUT_DIM + l4) = o;
    }
}

extern "C" void kernel_launch(void* const* d_in, const int* in_sizes, int n_in,
                              void* d_out, int out_size, void* d_ws, size_t ws_size,
                              hipStream_t stream)
{
    const float* x     = (const float*)d_in[0];
    const int*   ei    = (const int*)d_in[1];
    const float* beta  = (const float*)d_in[2];
    const float* Wg    = (const float*)d_in[3];
    const float* att_s = (const float*)d_in[4];
    const float* att_d = (const float*)d_in[5];
    const float* bias  = (const float*)d_in[6];
    const float* Wf    = (const float*)d_in[7];
    float* out = (float*)d_out;
    float* ws  = (float*)d_ws;

    if (ws_size < WS_FLOATS * sizeof(float)) return;

    ushort* hb     = (ushort*)(ws + OFF_HB);
    ushort* xb     = (ushort*)(ws + OFF_XB);
    ushort* Wc     = (ushort*)(ws + OFF_WC);
    float*  asrc   = ws + OFF_ASRC;
    float*  adst   = ws + OFF_ADST;
    float*  denom  = ws + OFF_DENOM;
    int*    count  = (int*)(ws + OFF_COUNT);
    int*    offs   = (int*)(ws + OFF_OFFS);
    int*    cursor = (int*)(ws + OFF_CURS);
    int*    bsum   = (int*)(ws + OFF_BSUM);
    float4* rec    = (float4*)(ws + OFF_REC);

    hipMemsetAsync(denom, 0, (size_t)N_NODES * sizeof(float), stream);
    hipMemsetAsync(count, 0, (size_t)N_NODES * sizeof(int), stream);

    convert_w<<<64, 256, 0, stream>>>(Wg, Wf, Wc);
    gemm_mfma<<<(N_NODES + 63) / 64, 256, 0, stream>>>(x, Wc, hb, xb);
    node_scalars<<<(N_NODES + 7) / 8, 256, 0, stream>>>(hb, att_s, att_d, asrc, adst);
    edge_alpha<<<N_EDGES / 256, 256, 0, stream>>>(ei, asrc, adst, denom, count);
    scan1<<<SCAN_BLOCKS, 256, 0, stream>>>(count, offs, bsum);
    scan2<<<1, 512, 0, stream>>>(bsum);
    scan3<<<SCAN_BLOCKS, 256, 0, stream>>>(offs, bsum, cursor);
    scatter_rec<<<N_EDGES / 256, 256, 0, stream>>>(ei, asrc, adst, denom, beta, cursor, rec);
    segment_reduce<<<(N_NODES * 64 + 255) / 256, 256, 0, stream>>>(hb, xb, rec, offs, count, bias, out);
}

// Round 4
// 487.976 us; speedup vs baseline: 6.5438x; 1.2147x over previous
//
#include <hip/hip_runtime.h>
#include <math.h>

#define N_NODES 100000
#define N_EDGES 1600000
#define IN_DIM 256
#define OUT_DIM 128
#define NEG_SLOPE 0.2f
#define LAMBDA 0.5f
#define EPS 1e-8f

#define FIX_SCALE 67108864.0f          // 2^26 fixed-point for alpha sum
#define FIX_INV   (1.0f / 67108864.0f)
#define CNT_SHIFT 46

// ---- workspace layout (float offsets; PACK offset even for 8B align) ----
#define OFF_HB    ((size_t)0)          // N*128 bf16 (ushort)  h
#define OFF_XB    ((size_t)6400000)    // N*128 bf16 (ushort)  xW_fixed
#define OFF_WC    ((size_t)12800000)   // 256x256 bf16
#define OFF_ASRC  ((size_t)12832768)   // N float
#define OFF_ADST  ((size_t)12932768)   // N float
#define OFF_PACK  ((size_t)13032768)   // N u64: count<<46 | alpha_fix_sum
#define OFF_COUNT ((size_t)13232768)   // N int
#define OFF_OFFS  ((size_t)13332768)   // N int
#define OFF_BSUM  ((size_t)13432768)   // 1024 int
#define OFF_TMP   ((size_t)13433792)   // E int4 (s,d,pos,alpha)  16B-aligned
#define OFF_REC   ((size_t)19833792)   // E float4 (s,c1,c2,_)
#define WS_FLOATS ((size_t)26233792)   // ~105 MB

#define SCAN_BLOCKS ((N_NODES + 255) / 256)   // 391

typedef __attribute__((ext_vector_type(8))) short bf16x8;
typedef __attribute__((ext_vector_type(4))) float f32x4;

__device__ __forceinline__ unsigned short f2b(float f) {
    unsigned u = __float_as_uint(f);
    u += 0x7FFFu + ((u >> 16) & 1u);   // RNE (inputs finite)
    return (unsigned short)(u >> 16);
}
__device__ __forceinline__ float b2f_lo(unsigned u) { return __uint_as_float(u << 16); }
__device__ __forceinline__ float b2f_hi(unsigned u) { return __uint_as_float(u & 0xFFFF0000u); }

// ============================================================
// K0: pack [Wg ; Wf] -> Wc bf16 256x256
// ============================================================
__global__ __launch_bounds__(256) void convert_w(
    const float* __restrict__ Wg, const float* __restrict__ Wf,
    ushort* __restrict__ Wc)
{
    int g = blockIdx.x * 256 + threadIdx.x;
    int e4  = g * 4;
    int row = e4 >> 8;
    int col = e4 & 255;
    const float* src = (row < 128) ? (Wg + (size_t)row * 256 + col)
                                   : (Wf + (size_t)(row - 128) * 256 + col);
    float4 v = *(const float4*)src;
    ushort4 p;
    p.x = f2b(v.x); p.y = f2b(v.y); p.z = f2b(v.z); p.w = f2b(v.w);
    *(ushort4*)(Wc + (size_t)row * 256 + col) = p;
}

// ============================================================
// K1: bf16 MFMA GEMM  [h | xw] = x @ Wc^T   (64 nodes x 256 cols / block)
// ============================================================
__global__ __launch_bounds__(256) void gemm_mfma(
    const float* __restrict__ x, const ushort* __restrict__ Wc,
    ushort* __restrict__ hb, ushort* __restrict__ xb)
{
    __shared__ ushort As[64 * 264];
    __shared__ ushort Bs[4 * 256 * 8];
    const int tid  = threadIdx.x;
    const int wv   = tid >> 6;
    const int lane = tid & 63;
    const int quad = lane >> 4;
    const int l16  = lane & 15;
    const int nb   = blockIdx.x * 64;

    f32x4 acc[4][4];
#pragma unroll
    for (int mt = 0; mt < 4; ++mt)
#pragma unroll
        for (int nt = 0; nt < 4; ++nt) acc[mt][nt] = (f32x4){0.f, 0.f, 0.f, 0.f};

#pragma unroll
    for (int it = 0; it < 16; ++it) {
        int f   = tid + it * 256;
        int row = f >> 6;
        int c4  = (f & 63) << 2;
        int gn  = nb + row; if (gn >= N_NODES) gn = N_NODES - 1;
        float4 v = *(const float4*)(x + (size_t)gn * IN_DIM + c4);
        ushort4 p;
        p.x = f2b(v.x); p.y = f2b(v.y); p.z = f2b(v.z); p.w = f2b(v.w);
        *(ushort4*)(&As[row * 264 + c4]) = p;
    }

    for (int kc = 0; kc < 256; kc += 32) {
        __syncthreads();
        {
            const int n = tid;
#pragma unroll
            for (int b = 0; b < 4; ++b) {
                bf16x8 w = *(const bf16x8*)(Wc + (size_t)n * 256 + kc + b * 8);
                *(bf16x8*)(&Bs[((size_t)b * 256 + n) * 8]) = w;
            }
        }
        __syncthreads();

        bf16x8 afr[4], bfr[4];
#pragma unroll
        for (int mt = 0; mt < 4; ++mt)
            afr[mt] = *(const bf16x8*)(&As[(mt * 16 + l16) * 264 + kc + quad * 8]);
#pragma unroll
        for (int nt = 0; nt < 4; ++nt) {
            int n = wv * 64 + nt * 16 + l16;
            bfr[nt] = *(const bf16x8*)(&Bs[((size_t)quad * 256 + n) * 8]);
        }
#pragma unroll
        for (int mt = 0; mt < 4; ++mt)
#pragma unroll
            for (int nt = 0; nt < 4; ++nt)
                acc[mt][nt] = __builtin_amdgcn_mfma_f32_16x16x32_bf16(
                    afr[mt], bfr[nt], acc[mt][nt], 0, 0, 0);
    }

    ushort* outp = (wv < 2) ? hb : xb;
    const int ncol0 = (wv & 1) * 64;
#pragma unroll
    for (int mt = 0; mt < 4; ++mt) {
#pragma unroll
        for (int nt = 0; nt < 4; ++nt) {
            int coln = ncol0 + nt * 16 + l16;
#pragma unroll
            for (int r = 0; r < 4; ++r) {
                int node = nb + mt * 16 + quad * 4 + r;
                if (node < N_NODES)
                    outp[(size_t)node * 128 + coln] = f2b(acc[mt][nt][r]);
            }
        }
    }
}

// ============================================================
// K2: per-node attention scalars
// ============================================================
__global__ __launch_bounds__(256) void node_scalars(
    const ushort* __restrict__ hb, const float* __restrict__ att_s,
    const float* __restrict__ att_d, float* __restrict__ a_src,
    float* __restrict__ a_dst)
{
    int node = blockIdx.x * 8 + (threadIdx.x >> 5);
    int l    = threadIdx.x & 31;
    if (node >= N_NODES) return;
    uint2 u = *(const uint2*)(hb + (size_t)node * 128 + l * 4);
    float f0 = b2f_lo(u.x), f1 = b2f_hi(u.x), f2 = b2f_lo(u.y), f3 = b2f_hi(u.y);
    float4 s = *(const float4*)(att_s + l * 4);
    float4 d = *(const float4*)(att_d + l * 4);
    float ss = f0 * s.x + f1 * s.y + f2 * s.z + f3 * s.w;
    float dd = f0 * d.x + f1 * d.y + f2 * d.z + f3 * d.w;
#pragma unroll
    for (int m = 1; m < 32; m <<= 1) {
        ss += __shfl_xor(ss, m);
        dd += __shfl_xor(dd, m);
    }
    if (l == 0) { a_src[node] = ss; a_dst[node] = dd; }
}

// ============================================================
// K3: edge prep — ONE u64 atomic per edge.
// pack[d] += (1<<46) | fix(alpha); returned old value gives pos (rank).
// tmp[e] = (s, d, pos, alpha_bits)
// ============================================================
__global__ __launch_bounds__(256) void edge_prep(
    const int* __restrict__ ei, const float* __restrict__ a_src,
    const float* __restrict__ a_dst, unsigned long long* __restrict__ pack,
    int4* __restrict__ tmp)
{
    int e = blockIdx.x * 256 + threadIdx.x;
    int s = ei[e];
    int d = ei[N_EDGES + e];
    s = s < 0 ? 0 : (s >= N_NODES ? N_NODES - 1 : s);
    d = d < 0 ? 0 : (d >= N_NODES ? N_NODES - 1 : d);
    float ev = a_src[s] + a_dst[d];
    ev = ev >= 0.f ? ev : NEG_SLOPE * ev;
    float al = 1.f / (1.f + expf(-ev));
    unsigned fix = (unsigned)(al * FIX_SCALE + 0.5f);
    unsigned long long old = atomicAdd(pack + d,
        ((unsigned long long)1 << CNT_SHIFT) | (unsigned long long)fix);
    int pos = (int)(old >> CNT_SHIFT);
    tmp[e] = make_int4(s, d, pos, __float_as_int(al));
}

// ============================================================
// K4a/b/c: exclusive scan of counts (extracted from pack) -> offs
// ============================================================
__global__ __launch_bounds__(256) void scan1(
    const unsigned long long* __restrict__ pack, int* __restrict__ count,
    int* __restrict__ offs, int* __restrict__ bsum)
{
    __shared__ int s[256];
    int i = blockIdx.x * 256 + threadIdx.x;
    int v = (i < N_NODES) ? (int)(pack[i] >> CNT_SHIFT) : 0;
    if (i < N_NODES) count[i] = v;
    s[threadIdx.x] = v;
    __syncthreads();
    for (int off = 1; off < 256; off <<= 1) {
        int t = (threadIdx.x >= off) ? s[threadIdx.x - off] : 0;
        __syncthreads();
        s[threadIdx.x] += t;
        __syncthreads();
    }
    if (i < N_NODES) offs[i] = s[threadIdx.x] - v;
    if (threadIdx.x == 255) bsum[blockIdx.x] = s[255];
}

__global__ __launch_bounds__(512) void scan2(int* __restrict__ bsum)
{
    __shared__ int s[512];
    int v = (threadIdx.x < SCAN_BLOCKS) ? bsum[threadIdx.x] : 0;
    s[threadIdx.x] = v;
    __syncthreads();
    for (int off = 1; off < 512; off <<= 1) {
        int t = (threadIdx.x >= off) ? s[threadIdx.x - off] : 0;
        __syncthreads();
        s[threadIdx.x] += t;
        __syncthreads();
    }
    if (threadIdx.x < SCAN_BLOCKS) bsum[threadIdx.x] = s[threadIdx.x] - v;
}

__global__ __launch_bounds__(256) void scan3(
    int* __restrict__ offs, const int* __restrict__ bsum)
{
    int i = blockIdx.x * 256 + threadIdx.x;
    if (i < N_NODES) offs[i] += bsum[blockIdx.x];
}

// ============================================================
// K5: scatter sorted records — NO atomics.
// slot = offs[d] + pos; denom from pack fixed-point sum.
// ============================================================
__global__ __launch_bounds__(256) void scatter_rec(
    const int4* __restrict__ tmp, const unsigned long long* __restrict__ pack,
    const int* __restrict__ offs, const float* __restrict__ beta,
    float4* __restrict__ rec)
{
    int e = blockIdx.x * 256 + threadIdx.x;
    int4 t = tmp[e];
    float al = __int_as_float(t.w);
    unsigned long long p = pack[t.y];
    float denom = (float)(p & (((unsigned long long)1 << CNT_SHIFT) - 1)) * FIX_INV;
    float c1 = LAMBDA * al / (denom + EPS);
    float c2 = (1.f - LAMBDA) * beta[e];
    int slot = offs[t.y] + t.z;
    rec[slot] = make_float4(__int_as_float(t.x), c1, c2, 0.f);
}

// ============================================================
// K6: segmented reduce — one wave per dst node, bf16 gathers, no atomics.
// ============================================================
__global__ __launch_bounds__(256) void segment_reduce(
    const ushort* __restrict__ hb, const ushort* __restrict__ xb,
    const float4* __restrict__ rec, const int* __restrict__ offs,
    const int* __restrict__ count, const float* __restrict__ bias,
    float* __restrict__ out)
{
    int wave = (blockIdx.x * 256 + threadIdx.x) >> 6;
    int lane = threadIdx.x & 63;
    if (wave >= N_NODES) return;
    int start = offs[wave];
    int cnt   = count[wave];
    const bool hhalf = lane < 32;
    const ushort* base = hhalf ? hb : xb;
    const int l4 = (lane & 31) * 4;

    float4 acc = make_float4(0.f, 0.f, 0.f, 0.f);
    int k = 0;
    for (; k + 2 <= cnt; k += 2) {
        float4 r0 = rec[start + k];
        float4 r1 = rec[start + k + 1];
        int   s0 = __float_as_int(r0.x);
        int   s1 = __float_as_int(r1.x);
        float c0 = hhalf ? r0.y : r0.z;
        float c1 = hhalf ? r1.y : r1.z;
        uint2 u0 = *(const uint2*)(base + (size_t)s0 * 128 + l4);
        uint2 u1 = *(const uint2*)(base + (size_t)s1 * 128 + l4);
        acc.x += c0 * b2f_lo(u0.x); acc.y += c0 * b2f_hi(u0.x);
        acc.z += c0 * b2f_lo(u0.y); acc.w += c0 * b2f_hi(u0.y);
        acc.x += c1 * b2f_lo(u1.x); acc.y += c1 * b2f_hi(u1.x);
        acc.z += c1 * b2f_lo(u1.y); acc.w += c1 * b2f_hi(u1.y);
    }
    if (k < cnt) {
        float4 r0 = rec[start + k];
        int   s0 = __float_as_int(r0.x);
        float c0 = hhalf ? r0.y : r0.z;
        uint2 u0 = *(const uint2*)(base + (size_t)s0 * 128 + l4);
        acc.x += c0 * b2f_lo(u0.x); acc.y += c0 * b2f_hi(u0.x);
        acc.z += c0 * b2f_lo(u0.y); acc.w += c0 * b2f_hi(u0.y);
    }

    acc.x += __shfl_xor(acc.x, 32);
    acc.y += __shfl_xor(acc.y, 32);
    acc.z += __shfl_xor(acc.z, 32);
    acc.w += __shfl_xor(acc.w, 32);

    if (hhalf) {
        float4 b = *(const float4*)(bias + l4);
        float4 o;
        o.x = acc.x + LAMBDA * b.x;
        o.y = acc.y + LAMBDA * b.y;
        o.z = acc.z + LAMBDA * b.z;
        o.w = acc.w + LAMBDA * b.w;
        o.x = o.x > 0.f ? o.x : expm1f(o.x);
        o.y = o.y > 0.f ? o.y : expm1f(o.y);
        o.z = o.z > 0.f ? o.z : expm1f(o.z);
        o.w = o.w > 0.f ? o.w : expm1f(o.w);
        *(float4*)(out + (size_t)wave * OUT_DIM + l4) = o;
    }
}

extern "C" void kernel_launch(void* const* d_in, const int* in_sizes, int n_in,
                              void* d_out, int out_size, void* d_ws, size_t ws_size,
                              hipStream_t stream)
{
    const float* x     = (const float*)d_in[0];
    const int*   ei    = (const int*)d_in[1];
    const float* beta  = (const float*)d_in[2];
    const float* Wg    = (const float*)d_in[3];
    const float* att_s = (const float*)d_in[4];
    const float* att_d = (const float*)d_in[5];
    const float* bias  = (const float*)d_in[6];
    const float* Wf    = (const float*)d_in[7];
    float* out = (float*)d_out;
    float* ws  = (float*)d_ws;

    if (ws_size < WS_FLOATS * sizeof(float)) return;

    ushort* hb   = (ushort*)(ws + OFF_HB);
    ushort* xb   = (ushort*)(ws + OFF_XB);
    ushort* Wc   = (ushort*)(ws + OFF_WC);
    float*  asrc = ws + OFF_ASRC;
    float*  adst = ws + OFF_ADST;
    unsigned long long* pack = (unsigned long long*)(ws + OFF_PACK);
    int*    count = (int*)(ws + OFF_COUNT);
    int*    offs  = (int*)(ws + OFF_OFFS);
    int*    bsum  = (int*)(ws + OFF_BSUM);
    int4*   tmp   = (int4*)(ws + OFF_TMP);
    float4* rec   = (float4*)(ws + OFF_REC);

    hipMemsetAsync(pack, 0, (size_t)N_NODES * sizeof(unsigned long long), stream);

    convert_w<<<64, 256, 0, stream>>>(Wg, Wf, Wc);
    gemm_mfma<<<(N_NODES + 63) / 64, 256, 0, stream>>>(x, Wc, hb, xb);
    node_scalars<<<(N_NODES + 7) / 8, 256, 0, stream>>>(hb, att_s, att_d, asrc, adst);
    edge_prep<<<N_EDGES / 256, 256, 0, stream>>>(ei, asrc, adst, pack, tmp);
    scan1<<<SCAN_BLOCKS, 256, 0, stream>>>(pack, count, offs, bsum);
    scan2<<<1, 512, 0, stream>>>(bsum);
    scan3<<<SCAN_BLOCKS, 256, 0, stream>>>(offs, bsum);
    scatter_rec<<<N_EDGES / 256, 256, 0, stream>>>(tmp, pack, offs, beta, rec);
    segment_reduce<<<(N_NODES * 64 + 255) / 256, 256, 0, stream>>>(hb, xb, rec, offs, count, bias, out);
}

// Round 5
// 482.887 us; speedup vs baseline: 6.6127x; 1.0105x over previous
//
#include <hip/hip_runtime.h>
#include <math.h>

#define N_NODES 100000
#define N_EDGES 1600000
#define IN_DIM 256
#define OUT_DIM 128
#define NEG_SLOPE 0.2f
#define LAMBDA 0.5f
#define EPS 1e-8f

#define FIX_SCALE 67108864.0f          // 2^26 fixed-point for alpha sum
#define FIX_INV   (1.0f / 67108864.0f)
#define CNT_SHIFT 46

// ---- workspace layout (float offsets) ----
#define OFF_HB    ((size_t)0)          // N*128 bf16 (ushort)  h
#define OFF_XB    ((size_t)6400000)    // N*128 bf16 (ushort)  xW_fixed
#define OFF_WC    ((size_t)12800000)   // 256x256 bf16, pre-swizzled Bs layout
#define OFF_ASRC  ((size_t)12832768)   // N float
#define OFF_ADST  ((size_t)12932768)   // N float
#define OFF_PACK  ((size_t)13032768)   // N u64: count<<46 | alpha_fix_sum
#define OFF_COUNT ((size_t)13232768)   // N int
#define OFF_OFFS  ((size_t)13332768)   // N int
#define OFF_BSUM  ((size_t)13432768)   // 1024 int
#define OFF_TMP   ((size_t)13433792)   // E int4 (s,d,pos,alpha)
#define OFF_REC   ((size_t)19833792)   // E float4 (s,c1,c2,_)
#define WS_FLOATS ((size_t)26233792)   // ~105 MB

#define SCAN_BLOCKS ((N_NODES + 255) / 256)   // 391

typedef __attribute__((ext_vector_type(8))) short bf16x8;
typedef __attribute__((ext_vector_type(4))) float f32x4;

__device__ __forceinline__ unsigned short f2b(float f) {
    unsigned u = __float_as_uint(f);
    u += 0x7FFFu + ((u >> 16) & 1u);   // RNE (inputs finite)
    return (unsigned short)(u >> 16);
}
__device__ __forceinline__ float b2f_lo(unsigned u) { return __uint_as_float(u << 16); }
__device__ __forceinline__ float b2f_hi(unsigned u) { return __uint_as_float(u & 0xFFFF0000u); }

// ============================================================
// K0: pack [Wg ; Wf] -> Wc2, PRE-SWIZZLED into the GEMM's Bs layout:
//   Wc2[ ((k>>3)*256 + n)*8 + (k&7) ] = W[n][k]   (n: 0-127 Wg, 128-255 Wf)
// so per-K-chunk staging is a straight coalesced 16 KB copy.
// ============================================================
__global__ __launch_bounds__(256) void convert_w2(
    const float* __restrict__ Wg, const float* __restrict__ Wf,
    ushort* __restrict__ Wc2)
{
    int g  = blockIdx.x * 256 + threadIdx.x;   // 0..8191 chunk id
    int n  = g & 255;
    int kb = g >> 8;                           // 0..31
    const float* src = (n < 128) ? (Wg + (size_t)n * 256 + kb * 8)
                                 : (Wf + (size_t)(n - 128) * 256 + kb * 8);
    float4 a = *(const float4*)(src);
    float4 b = *(const float4*)(src + 4);
    ushort p[8];
    p[0] = f2b(a.x); p[1] = f2b(a.y); p[2] = f2b(a.z); p[3] = f2b(a.w);
    p[4] = f2b(b.x); p[5] = f2b(b.y); p[6] = f2b(b.z); p[7] = f2b(b.w);
    *(bf16x8*)(Wc2 + (size_t)g * 8) = *(bf16x8*)p;
}

// ============================================================
// K1: bf16 MFMA GEMM [h | xw] = x @ W^T  (64 nodes x 256 cols / block)
// + LDS-transposed epilogue (coalesced bf16 stores) + fused node scalars
// ============================================================
__global__ __launch_bounds__(256) void gemm_mfma(
    const float* __restrict__ x, const ushort* __restrict__ Wc2,
    const float* __restrict__ att_s, const float* __restrict__ att_d,
    ushort* __restrict__ hb, ushort* __restrict__ xb,
    float* __restrict__ a_src, float* __restrict__ a_dst)
{
    __shared__ ushort As[64 * 264];      // 33.8 KB (reused by epilogue)
    __shared__ ushort Bs[4 * 256 * 8];   // 16 KB
    const int tid  = threadIdx.x;
    const int wv   = tid >> 6;
    const int lane = tid & 63;
    const int quad = lane >> 4;
    const int l16  = lane & 15;
    const int nb   = blockIdx.x * 64;

    f32x4 acc[4][4];
#pragma unroll
    for (int mt = 0; mt < 4; ++mt)
#pragma unroll
        for (int nt = 0; nt < 4; ++nt) acc[mt][nt] = (f32x4){0.f, 0.f, 0.f, 0.f};

    // ---- stage A: 64 rows x 256 k, fp32 -> bf16 ----
#pragma unroll
    for (int it = 0; it < 16; ++it) {
        int f   = tid + it * 256;
        int row = f >> 6;
        int c4  = (f & 63) << 2;
        int gn  = nb + row; if (gn >= N_NODES) gn = N_NODES - 1;
        float4 v = *(const float4*)(x + (size_t)gn * IN_DIM + c4);
        ushort4 p;
        p.x = f2b(v.x); p.y = f2b(v.y); p.z = f2b(v.z); p.w = f2b(v.w);
        *(ushort4*)(&As[row * 264 + c4]) = p;
    }

    for (int kc = 0; kc < 256; kc += 32) {
        __syncthreads();
        // ---- stage B chunk: straight 16 KB coalesced copy ----
#pragma unroll
        for (int it = 0; it < 4; ++it) {
            int off = (it * 256 + tid) * 8;
            *(bf16x8*)(&Bs[off]) = *(const bf16x8*)(Wc2 + (size_t)kc * 256 + off);
        }
        __syncthreads();

        bf16x8 afr[4], bfr[4];
#pragma unroll
        for (int mt = 0; mt < 4; ++mt)
            afr[mt] = *(const bf16x8*)(&As[(mt * 16 + l16) * 264 + kc + quad * 8]);
#pragma unroll
        for (int nt = 0; nt < 4; ++nt) {
            int n = (wv & 1) * 64 + ((wv >> 1) << 7) + nt * 16 + l16;  // wv0:0-63 h, wv1:64-127 h, wv2/3: xw
            bfr[nt] = *(const bf16x8*)(&Bs[((size_t)quad * 256 + n) * 8]);
        }
#pragma unroll
        for (int mt = 0; mt < 4; ++mt)
#pragma unroll
            for (int nt = 0; nt < 4; ++nt)
                acc[mt][nt] = __builtin_amdgcn_mfma_f32_16x16x32_bf16(
                    afr[mt], bfr[nt], acc[mt][nt], 0, 0, 0);
    }

    // ---- epilogue: acc -> LDS (reuse As as 64 x [h|xw] ushort rows) ----
    __syncthreads();
    {
        const int colbase = (wv >> 1) * 128 + (wv & 1) * 64;  // matches bfr n mapping
#pragma unroll
        for (int mt = 0; mt < 4; ++mt)
#pragma unroll
            for (int nt = 0; nt < 4; ++nt) {
                int col = colbase + nt * 16 + l16;
#pragma unroll
                for (int r = 0; r < 4; ++r)
                    As[(mt * 16 + quad * 4 + r) * 264 + col] = f2b(acc[mt][nt][r]);
            }
    }
    __syncthreads();

    // ---- coalesced stores + fused per-node attention scalars ----
    {
        const int row = tid >> 2;
        const int q   = tid & 3;
        const int gn  = nb + row;
        bf16x8 v[8];
#pragma unroll
        for (int j = 0; j < 8; ++j)
            v[j] = *(const bf16x8*)(&As[row * 264 + q * 64 + j * 8]);
        if (gn < N_NODES) {
            ushort* dst = (q < 2) ? (hb + (size_t)gn * 128 + q * 64)
                                  : (xb + (size_t)gn * 128 + (q - 2) * 64);
#pragma unroll
            for (int j = 0; j < 8; ++j)
                *(bf16x8*)(dst + j * 8) = v[j];
        }
        if (q < 2) {
            const float4* as4 = (const float4*)att_s;
            const float4* ad4 = (const float4*)att_d;
            float ss = 0.f, dd = 0.f;
#pragma unroll
            for (int j = 0; j < 8; ++j) {
#pragma unroll
                for (int hv = 0; hv < 2; ++hv) {
                    float4 sa = as4[q * 16 + j * 2 + hv];
                    float4 da = ad4[q * 16 + j * 2 + hv];
                    unsigned u0 = ((const unsigned*)&v[j])[hv * 2];
                    unsigned u1 = ((const unsigned*)&v[j])[hv * 2 + 1];
                    float f0 = b2f_lo(u0), f1 = b2f_hi(u0), f2 = b2f_lo(u1), f3 = b2f_hi(u1);
                    ss += f0 * sa.x + f1 * sa.y + f2 * sa.z + f3 * sa.w;
                    dd += f0 * da.x + f1 * da.y + f2 * da.z + f3 * da.w;
                }
            }
            ss += __shfl_xor(ss, 1);
            dd += __shfl_xor(dd, 1);
            if (q == 0 && gn < N_NODES) { a_src[gn] = ss; a_dst[gn] = dd; }
        }
    }
}

// ============================================================
// K3: edge prep — 4 edges/thread (stride-256 coalesced), one u64
// atomic per edge, 4 independent chains in flight.
// ============================================================
__global__ __launch_bounds__(256) void edge_prep(
    const int* __restrict__ ei, const float* __restrict__ a_src,
    const float* __restrict__ a_dst, unsigned long long* __restrict__ pack,
    int4* __restrict__ tmp)
{
    const int bb = blockIdx.x * 1024 + threadIdx.x;
#pragma unroll
    for (int k = 0; k < 4; ++k) {
        int e = bb + k * 256;
        if (e >= N_EDGES) break;
        int s = ei[e];
        int d = ei[N_EDGES + e];
        s = s < 0 ? 0 : (s >= N_NODES ? N_NODES - 1 : s);
        d = d < 0 ? 0 : (d >= N_NODES ? N_NODES - 1 : d);
        float ev = a_src[s] + a_dst[d];
        ev = ev >= 0.f ? ev : NEG_SLOPE * ev;
        float al = 1.f / (1.f + __expf(-ev));
        unsigned fix = (unsigned)(al * FIX_SCALE + 0.5f);
        unsigned long long old = atomicAdd(pack + d,
            ((unsigned long long)1 << CNT_SHIFT) | (unsigned long long)fix);
        int pos = (int)(old >> CNT_SHIFT);
        tmp[e] = make_int4(s, d, pos, __float_as_int(al));
    }
}

// ============================================================
// K4a/b/c: exclusive scan of counts -> offs
// ============================================================
__global__ __launch_bounds__(256) void scan1(
    const unsigned long long* __restrict__ pack, int* __restrict__ count,
    int* __restrict__ offs, int* __restrict__ bsum)
{
    __shared__ int s[256];
    int i = blockIdx.x * 256 + threadIdx.x;
    int v = (i < N_NODES) ? (int)(pack[i] >> CNT_SHIFT) : 0;
    if (i < N_NODES) count[i] = v;
    s[threadIdx.x] = v;
    __syncthreads();
    for (int off = 1; off < 256; off <<= 1) {
        int t = (threadIdx.x >= off) ? s[threadIdx.x - off] : 0;
        __syncthreads();
        s[threadIdx.x] += t;
        __syncthreads();
    }
    if (i < N_NODES) offs[i] = s[threadIdx.x] - v;
    if (threadIdx.x == 255) bsum[blockIdx.x] = s[255];
}

__global__ __launch_bounds__(512) void scan2(int* __restrict__ bsum)
{
    __shared__ int s[512];
    int v = (threadIdx.x < SCAN_BLOCKS) ? bsum[threadIdx.x] : 0;
    s[threadIdx.x] = v;
    __syncthreads();
    for (int off = 1; off < 512; off <<= 1) {
        int t = (threadIdx.x >= off) ? s[threadIdx.x - off] : 0;
        __syncthreads();
        s[threadIdx.x] += t;
        __syncthreads();
    }
    if (threadIdx.x < SCAN_BLOCKS) bsum[threadIdx.x] = s[threadIdx.x] - v;
}

__global__ __launch_bounds__(256) void scan3(
    int* __restrict__ offs, const int* __restrict__ bsum)
{
    int i = blockIdx.x * 256 + threadIdx.x;
    if (i < N_NODES) offs[i] += bsum[blockIdx.x];
}

// ============================================================
// K5: scatter sorted records — no atomics
// ============================================================
__global__ __launch_bounds__(256) void scatter_rec(
    const int4* __restrict__ tmp, const unsigned long long* __restrict__ pack,
    const int* __restrict__ offs, const float* __restrict__ beta,
    float4* __restrict__ rec)
{
    int e = blockIdx.x * 256 + threadIdx.x;
    int4 t = tmp[e];
    float al = __int_as_float(t.w);
    unsigned long long p = pack[t.y];
    float denom = (float)(p & (((unsigned long long)1 << CNT_SHIFT) - 1)) * FIX_INV;
    float c1 = LAMBDA * al / (denom + EPS);
    float c2 = (1.f - LAMBDA) * beta[e];
    int slot = offs[t.y] + t.z;
    rec[slot] = make_float4(__int_as_float(t.x), c1, c2, 0.f);
}

// ============================================================
// K6: segmented reduce v2 — one wave per dst, 2 edges per iteration.
// 16 lanes per half-row, uint4 (8 bf16) per lane, 2x unrolled.
// lane = sub(1b: which edge) | half(1b: h/xw) | li(4b: col/8)
// ============================================================
__global__ __launch_bounds__(256) void segment_reduce(
    const ushort* __restrict__ hb, const ushort* __restrict__ xb,
    const float4* __restrict__ rec, const int* __restrict__ offs,
    const int* __restrict__ count, const float* __restrict__ bias,
    float* __restrict__ out)
{
    int wave = (blockIdx.x * 256 + threadIdx.x) >> 6;
    int lane = threadIdx.x & 63;
    if (wave >= N_NODES) return;
    const int start = offs[wave];
    const int cnt   = count[wave];
    const int sub  = lane >> 5;
    const int half = (lane >> 4) & 1;
    const int li   = lane & 15;
    const ushort* __restrict__ base = half ? xb : hb;

    float av[8] = {0.f, 0.f, 0.f, 0.f, 0.f, 0.f, 0.f, 0.f};
    int k = 0;
    for (; k + 4 <= cnt; k += 4) {
        float4 rA = rec[start + k + sub];
        float4 rB = rec[start + k + 2 + sub];
        int   sA = __float_as_int(rA.x);
        int   sB = __float_as_int(rB.x);
        float cA = half ? rA.z : rA.y;
        float cB = half ? rB.z : rB.y;
        uint4 uA = *(const uint4*)(base + (size_t)sA * 128 + li * 8);
        uint4 uB = *(const uint4*)(base + (size_t)sB * 128 + li * 8);
        av[0] += cA * b2f_lo(uA.x); av[1] += cA * b2f_hi(uA.x);
        av[2] += cA * b2f_lo(uA.y); av[3] += cA * b2f_hi(uA.y);
        av[4] += cA * b2f_lo(uA.z); av[5] += cA * b2f_hi(uA.z);
        av[6] += cA * b2f_lo(uA.w); av[7] += cA * b2f_hi(uA.w);
        av[0] += cB * b2f_lo(uB.x); av[1] += cB * b2f_hi(uB.x);
        av[2] += cB * b2f_lo(uB.y); av[3] += cB * b2f_hi(uB.y);
        av[4] += cB * b2f_lo(uB.z); av[5] += cB * b2f_hi(uB.z);
        av[6] += cB * b2f_lo(uB.w); av[7] += cB * b2f_hi(uB.w);
    }
    for (; k < cnt; k += 2) {
        int kk  = k + sub;
        int idx = start + (kk < cnt ? kk : cnt - 1);
        float4 r = rec[idx];
        int   s = __float_as_int(r.x);
        float c = half ? r.z : r.y;
        c = (kk < cnt) ? c : 0.f;
        uint4 u = *(const uint4*)(base + (size_t)s * 128 + li * 8);
        av[0] += c * b2f_lo(u.x); av[1] += c * b2f_hi(u.x);
        av[2] += c * b2f_lo(u.y); av[3] += c * b2f_hi(u.y);
        av[4] += c * b2f_lo(u.z); av[5] += c * b2f_hi(u.z);
        av[6] += c * b2f_lo(u.w); av[7] += c * b2f_hi(u.w);
    }

#pragma unroll
    for (int j = 0; j < 8; ++j) av[j] += __shfl_xor(av[j], 32);  // pair combine
#pragma unroll
    for (int j = 0; j < 8; ++j) av[j] += __shfl_xor(av[j], 16);  // h + xw combine

    if (lane < 16) {
        const float4* b4 = (const float4*)(bias + li * 8);
        float4 b0 = b4[0], b1 = b4[1];
        float o[8];
        o[0] = av[0] + LAMBDA * b0.x; o[1] = av[1] + LAMBDA * b0.y;
        o[2] = av[2] + LAMBDA * b0.z; o[3] = av[3] + LAMBDA * b0.w;
        o[4] = av[4] + LAMBDA * b1.x; o[5] = av[5] + LAMBDA * b1.y;
        o[6] = av[6] + LAMBDA * b1.z; o[7] = av[7] + LAMBDA * b1.w;
#pragma unroll
        for (int j = 0; j < 8; ++j) o[j] = o[j] > 0.f ? o[j] : expm1f(o[j]);
        float* op = out + (size_t)wave * OUT_DIM + li * 8;
        *(float4*)(op)     = make_float4(o[0], o[1], o[2], o[3]);
        *(float4*)(op + 4) = make_float4(o[4], o[5], o[6], o[7]);
    }
}

extern "C" void kernel_launch(void* const* d_in, const int* in_sizes, int n_in,
                              void* d_out, int out_size, void* d_ws, size_t ws_size,
                              hipStream_t stream)
{
    const float* x     = (const float*)d_in[0];
    const int*   ei    = (const int*)d_in[1];
    const float* beta  = (const float*)d_in[2];
    const float* Wg    = (const float*)d_in[3];
    const float* att_s = (const float*)d_in[4];
    const float* att_d = (const float*)d_in[5];
    const float* bias  = (const float*)d_in[6];
    const float* Wf    = (const float*)d_in[7];
    float* out = (float*)d_out;
    float* ws  = (float*)d_ws;

    if (ws_size < WS_FLOATS * sizeof(float)) return;

    ushort* hb   = (ushort*)(ws + OFF_HB);
    ushort* xb   = (ushort*)(ws + OFF_XB);
    ushort* Wc2  = (ushort*)(ws + OFF_WC);
    float*  asrc = ws + OFF_ASRC;
    float*  adst = ws + OFF_ADST;
    unsigned long long* pack = (unsigned long long*)(ws + OFF_PACK);
    int*    count = (int*)(ws + OFF_COUNT);
    int*    offs  = (int*)(ws + OFF_OFFS);
    int*    bsum  = (int*)(ws + OFF_BSUM);
    int4*   tmp   = (int4*)(ws + OFF_TMP);
    float4* rec   = (float4*)(ws + OFF_REC);

    hipMemsetAsync(pack, 0, (size_t)N_NODES * sizeof(unsigned long long), stream);

    convert_w2<<<32, 256, 0, stream>>>(Wg, Wf, Wc2);
    gemm_mfma<<<(N_NODES + 63) / 64, 256, 0, stream>>>(x, Wc2, att_s, att_d, hb, xb, asrc, adst);
    edge_prep<<<(N_EDGES + 1023) / 1024, 256, 0, stream>>>(ei, asrc, adst, pack, tmp);
    scan1<<<SCAN_BLOCKS, 256, 0, stream>>>(pack, count, offs, bsum);
    scan2<<<1, 512, 0, stream>>>(bsum);
    scan3<<<SCAN_BLOCKS, 256, 0, stream>>>(offs, bsum);
    scatter_rec<<<N_EDGES / 256, 256, 0, stream>>>(tmp, pack, offs, beta, rec);
    segment_reduce<<<(N_NODES * 64 + 255) / 256, 256, 0, stream>>>(hb, xb, rec, offs, count, bias, out);
}